// Round 12
// baseline (295.984 us; speedup 1.0000x reference)
//
#include <hip/hip_runtime.h>
#include <hip/hip_bf16.h>
#include <stdint.h>

#define BATCH  8192
#define DIN    2048
#define DOUT   2048
#define NB     256
#define KSEL   26      // ceil(0.1*256)
#define GDELTA 1e-4f   // top-k boundary refine threshold

typedef __attribute__((ext_vector_type(4))) float f32x4;
typedef __attribute__((ext_vector_type(8))) __bf16 bf16x8;
typedef __attribute__((ext_vector_type(8))) unsigned short u16x8;

__device__ __forceinline__ float bf2f(unsigned short u){
  union { unsigned int i; float f; } v; v.i = ((unsigned int)u) << 16; return v.f;
}
__device__ __forceinline__ unsigned short f2bf_c(float f){
  __bf16 b = (__bf16)f;
  union { __bf16 b; unsigned short u; } v; v.b = b; return v.u;
}
// async global->LDS, 16B/lane; LDS dest wave-uniform base.
__device__ __forceinline__ void gload16(const unsigned short* g, unsigned short* l){
  __builtin_amdgcn_global_load_lds(
      (const __attribute__((address_space(1))) void*)g,
      (__attribute__((address_space(3))) void*)l, 16, 0, 0);
}

// BK=32 tile images (T21): elem (row, k) of a [R][32] bf16 tile at u16 offset
// row*32 + ((c3 ^ ((row>>1)&3))<<3) + (k&7), c3 = (k&31)>>3. Frag reads
// (16 rows x b128) land 2-way per bank = free. Same image in global so
// global_load_lds with linear dest reproduces it byte-for-byte.

// ---------------- K0a: x -> tiled hi/lo bf16 (xht = bf16(x), xlt = resid) ---
__global__ __launch_bounds__(256) void conv_xhl(const float* __restrict__ x,
    unsigned short* __restrict__ xht, unsigned short* __restrict__ xlt)
{
  const int r    = threadIdx.x >> 2;        // 0..63
  const int cq   = threadIdx.x & 3;
  const int grow = blockIdx.x * 64 + r;
  const int kp   = (blockIdx.y << 2) + cq;  // global 32k-step 0..63
  const int lrow = grow & 127;
  const int sw   = (lrow >> 1) & 3;
  const size_t base = ((size_t)(grow >> 7) * 64 + kp) * 4096 + lrow * 32;
  const float* xp = &x[(size_t)grow * DIN + kp * 32];
  #pragma unroll
  for (int c3 = 0; c3 < 4; c3++){
    f32x4 a0 = *(const f32x4*)(xp + c3 * 8);
    f32x4 a1 = *(const f32x4*)(xp + c3 * 8 + 4);
    u16x8 hi, lo;
    #pragma unroll
    for (int j = 0; j < 4; j++){
      const __bf16 h0 = (__bf16)a0[j];
      const __bf16 h1 = (__bf16)a1[j];
      union { __bf16 b; unsigned short u; } u0, u1; u0.b = h0; u1.b = h1;
      hi[j] = u0.u; hi[4 + j] = u1.u;
      lo[j]     = f2bf_c(a0[j] - (float)h0);
      lo[4 + j] = f2bf_c(a1[j] - (float)h1);
    }
    const int off = (c3 ^ sw) << 3;
    *(u16x8*)&xht[base + off] = hi;
    *(u16x8*)&xlt[base + off] = lo;
  }
}

// ---------------- K0b: W -> tiled-swizzled bf16 [q][kp][128*32] -------------
__global__ __launch_bounds__(256) void conv_wt2(const float* __restrict__ w,
                                                unsigned short* __restrict__ wtt)
{
  __shared__ float tl[64][65];
  const int k0 = blockIdx.x * 64;
  const int n0 = blockIdx.y * 64;
  const int c  = threadIdx.x & 63;
  const int r4 = threadIdx.x >> 6;
  #pragma unroll
  for (int i = 0; i < 16; i++){
    const int r = r4 * 16 + i;
    tl[r][c] = w[(size_t)(k0 + r) * DOUT + n0 + c];
  }
  __syncthreads();
  const int n  = threadIdx.x & 63;
  const int cp = threadIdx.x >> 6;
  const int gn = n0 + n;
  const int q  = gn >> 7;
  const int ln = gn & 127;
  const int sw = (ln >> 1) & 3;
  #pragma unroll
  for (int u = 0; u < 2; u++){
    const int cc = cp * 2 + u;              // 8k-chunk within 64k
    const int kp = (k0 >> 5) + (cc >> 2);
    const int c3 = cc & 3;
    u16x8 o;
    #pragma unroll
    for (int j = 0; j < 8; j++) o[j] = f2bf_c(tl[cc * 8 + j][n]);
    *(u16x8*)&wtt[((size_t)q * 64 + kp) * 4096 + ln * 32 + ((c3 ^ sw) << 3)] = o;
  }
}

// ---------------- K0c: gw -> tiled-swizzled hi/lo [ct][kp][64*32] -----------
__global__ __launch_bounds__(256) void conv_gwt2(const float* __restrict__ gw,
    unsigned short* __restrict__ ght, unsigned short* __restrict__ glt)
{
  __shared__ float tl[64][65];
  const int k0 = blockIdx.x * 64;
  const int c0 = blockIdx.y * 64;
  const int c  = threadIdx.x & 63;
  const int r4 = threadIdx.x >> 6;
  #pragma unroll
  for (int i = 0; i < 16; i++){
    const int r = r4 * 16 + i;
    tl[r][c] = gw[(size_t)(k0 + r) * NB + c0 + c];
  }
  __syncthreads();
  const int ln = threadIdx.x & 63;
  const int cp = threadIdx.x >> 6;
  const int ct = blockIdx.y;
  const int sw = (ln >> 1) & 3;
  #pragma unroll
  for (int u = 0; u < 2; u++){
    const int cc = cp * 2 + u;
    const int kp = (k0 >> 5) + (cc >> 2);
    const int c3 = cc & 3;
    u16x8 hi, lo;
    #pragma unroll
    for (int j = 0; j < 8; j++){
      const float v = tl[cc * 8 + j][ln];
      const __bf16 hb = (__bf16)v;
      union { __bf16 b; unsigned short u; } uh; uh.b = hb;
      hi[j] = uh.u;
      lo[j] = f2bf_c(v - (float)hb);
    }
    const size_t base = ((size_t)ct * 64 + kp) * 2048 + ln * 32;
    const int off = (c3 ^ sw) << 3;
    *(u16x8*)&ght[base + off] = hi;
    *(u16x8*)&glt[base + off] = lo;
  }
}

// ---------------- K1: gate GEMM v8 — full-width blocks, dbuf DMA ------------
// Block = 64 b-rows x ALL 256 c-cols, BK=32, K-split 2 -> grid (128,2).
// Every xht/xlt byte read exactly once grid-wide (no c-tile redundancy);
// ght/glt (4MB) come from L2. Double-buffered global_load_lds (main_v5's
// verified overlap). 4 waves (2bw x 2cw), wave = 32b x 128c: 48 MFMA per
// drain vs 10 DMA issues. Accumulation k-order and term order (hh, lh, hl
// per BK=32 chunk) identical to R10/R11 -> gate values bit-identical.
__global__ __launch_bounds__(256) void gate_v8(
    const unsigned short* __restrict__ xht,
    const unsigned short* __restrict__ xlt,
    const unsigned short* __restrict__ ght,
    const unsigned short* __restrict__ glt,
    float* __restrict__ part)
{
  __shared__ unsigned short Ah[2][2048], Al[2][2048];   // 16 KB
  __shared__ unsigned short Bh[2][8192], Bl[2][8192];   // 64 KB

  const int bt   = blockIdx.x;          // 64-row b-tile 0..127
  const int z    = blockIdx.y;          // K-split 0/1
  const int b0   = bt * 64;
  const int t    = threadIdx.x;
  const int lane = t & 63;
  const int wid  = t >> 6;
  const int bw   = wid & 1;             // wave rows bw*32
  const int cw   = wid >> 1;            // wave cols cw*128
  const int l15  = lane & 15;
  const int l4   = lane >> 4;

  f32x4 acc[2][8];
  #pragma unroll
  for (int m = 0; m < 2; m++)
    #pragma unroll
    for (int n = 0; n < 8; n++) acc[m][n] = (f32x4)0.0f;

  // read offsets: A local rows 0..63 (half of a 128-row image; swizzle is
  // self-consistent since the 64-row offset is a multiple of 32 rows)
  int aoff[2], boff[8];
  #pragma unroll
  for (int m = 0; m < 2; m++){
    const int am = bw * 32 + m * 16 + l15;
    aoff[m] = am * 32 + ((l4 ^ ((am >> 1) & 3)) << 3);
  }
  #pragma unroll
  for (int n = 0; n < 8; n++){
    const int c  = cw * 128 + n * 16 + l15;
    const int ln = c & 63;
    boff[n] = (c >> 6) * 2048 + ln * 32 + ((l4 ^ ((ln >> 1) & 3)) << 3);
  }

  auto GLOAD = [&](int bb, int s){
    // A: our 64 rows = u16 range [(bt&1)*2048, +2048) of image ((bt>>1)*64+kp)
    const size_t ak = ((size_t)(bt >> 1) * 64 + z * 32 + s) * 4096 + (bt & 1) * 2048;
    gload16(xht + ak + wid * 512 + lane * 8, &Ah[bb][wid * 512]);
    gload16(xlt + ak + wid * 512 + lane * 8, &Al[bb][wid * 512]);
    // B: 4 ct-tiles (2048 u16 each) concatenated; 16 slots, 4 per wave
    #pragma unroll
    for (int i = 0; i < 4; i++){
      const int slot = wid * 4 + i;
      const size_t bk = ((size_t)(slot >> 2) * 64 + z * 32 + s) * 2048 + (slot & 3) * 512;
      gload16(ght + bk + lane * 8, &Bh[bb][slot * 512]);
      gload16(glt + bk + lane * 8, &Bl[bb][slot * 512]);
    }
  };

  GLOAD(0, 0);
  int buf = 0;
  #pragma unroll 1
  for (int s = 0; s < 32; s++){
    __syncthreads();                    // DMA(buf) drained; prev reads of buf^1 done
    if (s < 31) GLOAD(buf ^ 1, s + 1); // in flight during compute
    bf16x8 ah[2], al[2];
    #pragma unroll
    for (int m = 0; m < 2; m++){
      ah[m] = *(const bf16x8*)&Ah[buf][aoff[m]];
      al[m] = *(const bf16x8*)&Al[buf][aoff[m]];
    }
    #pragma unroll
    for (int n = 0; n < 8; n++){
      const bf16x8 bh = *(const bf16x8*)&Bh[buf][boff[n]];
      const bf16x8 bl = *(const bf16x8*)&Bl[buf][boff[n]];
      #pragma unroll
      for (int m = 0; m < 2; m++){
        acc[m][n] = __builtin_amdgcn_mfma_f32_16x16x32_bf16(ah[m], bh, acc[m][n], 0, 0, 0);
        acc[m][n] = __builtin_amdgcn_mfma_f32_16x16x32_bf16(al[m], bh, acc[m][n], 0, 0, 0);
        acc[m][n] = __builtin_amdgcn_mfma_f32_16x16x32_bf16(ah[m], bl, acc[m][n], 0, 0, 0);
      }
    }
    buf ^= 1;
  }

  float* dst = part + (size_t)z * BATCH * NB;
  #pragma unroll
  for (int m = 0; m < 2; m++){
    const int brow = b0 + bw * 32 + m * 16 + l4 * 4;
    #pragma unroll
    for (int n = 0; n < 8; n++){
      const int ccol = cw * 128 + n * 16 + l15;
      #pragma unroll
      for (int r = 0; r < 4; r++)
        dst[(size_t)(brow + r) * NB + ccol] = acc[m][n][r];
    }
  }
}

// ---------------- K2: sum 2 partials, top-26 + renorm + boundary flag -------
__global__ __launch_bounds__(256) void topk(float* __restrict__ part,
    const float* __restrict__ gb, int* __restrict__ flags)
{
  const int lane = threadIdx.x & 63;
  const int row  = blockIdx.x * 4 + (threadIdx.x >> 6);
  f32x4* p0 = (f32x4*)&part[(size_t)row * NB];
  const f32x4* p1 = (const f32x4*)&part[(size_t)(BATCH + row) * NB];
  const f32x4* gbv = (const f32x4*)gb;
  f32x4 v = p0[lane] + p1[lane] + gbv[lane];

  const float NEG = -3.402823466e38f;
  float w0 = v[0], w1 = v[1], w2 = v[2], w3 = v[3];
  float thr = 0.f, nxt = 0.f;
  for (int it = 0; it < KSEL + 1; it++){
    float lm = fmaxf(fmaxf(w0, w1), fmaxf(w2, w3));
    float wm = lm;
    #pragma unroll
    for (int off = 32; off; off >>= 1) wm = fmaxf(wm, __shfl_xor(wm, off, 64));
    unsigned long long ball = __ballot(lm == wm);
    int first = __ffsll(ball) - 1;
    if (lane == first){
      if      (w0 == wm) w0 = NEG;
      else if (w1 == wm) w1 = NEG;
      else if (w2 == wm) w2 = NEG;
      else               w3 = NEG;
    }
    if (it < KSEL) thr = wm; else nxt = wm;
  }
  if (lane == 0) flags[row] = (thr - nxt < GDELTA) ? 1 : 0;

  float s = 0.f;
  #pragma unroll
  for (int j = 0; j < 4; j++) s += (v[j] >= thr) ? v[j] : 0.f;
  #pragma unroll
  for (int off = 32; off; off >>= 1) s += __shfl_xor(s, off, 64);
  const float d = s * (1.0f / NB);
  f32x4 o;
  #pragma unroll
  for (int j = 0; j < 4; j++) o[j] = (v[j] >= thr) ? v[j] / d : 0.f;
  p0[lane] = o;
}

// ---------------- K2b: exact recompute of boundary-ambiguous rows -----------
__global__ __launch_bounds__(256) void refine(
    const float* __restrict__ x, const float* __restrict__ gw,
    const float* __restrict__ gb, const int* __restrict__ flags,
    float* __restrict__ part)
{
  const int lane = threadIdx.x & 63;
  const int row  = blockIdx.x * 4 + (threadIdx.x >> 6);
  if (!flags[row]) return;

  f32x4 acc0 = (f32x4)0.f, acc1 = (f32x4)0.f;
  const float* xp = &x[(size_t)row * DIN];
  #pragma unroll 8
  for (int k = 0; k < 1024; k++){
    const float xv = xp[k];
    const f32x4 wv = *(const f32x4*)&gw[(size_t)k * NB + lane * 4];
    #pragma unroll
    for (int j = 0; j < 4; j++) acc0[j] = fmaf(xv, wv[j], acc0[j]);
  }
  #pragma unroll 8
  for (int k = 1024; k < 2048; k++){
    const float xv = xp[k];
    const f32x4 wv = *(const f32x4*)&gw[(size_t)k * NB + lane * 4];
    #pragma unroll
    for (int j = 0; j < 4; j++) acc1[j] = fmaf(xv, wv[j], acc1[j]);
  }
  const f32x4 gbv = *(const f32x4*)&gb[lane * 4];
  f32x4 v;
  #pragma unroll
  for (int j = 0; j < 4; j++) v[j] = acc0[j] + acc1[j] + gbv[j];

  const float NEG = -3.402823466e38f;
  float w0 = v[0], w1 = v[1], w2 = v[2], w3 = v[3];
  float thr = 0.f;
  for (int it = 0; it < KSEL; it++){
    float lm = fmaxf(fmaxf(w0, w1), fmaxf(w2, w3));
    float wm = lm;
    #pragma unroll
    for (int off = 32; off; off >>= 1) wm = fmaxf(wm, __shfl_xor(wm, off, 64));
    unsigned long long ball = __ballot(lm == wm);
    int first = __ffsll(ball) - 1;
    if (lane == first){
      if      (w0 == wm) w0 = NEG;
      else if (w1 == wm) w1 = NEG;
      else if (w2 == wm) w2 = NEG;
      else               w3 = NEG;
    }
    thr = wm;
  }
  float s = 0.f;
  #pragma unroll
  for (int j = 0; j < 4; j++) s += (v[j] >= thr) ? v[j] : 0.f;
  #pragma unroll
  for (int off = 32; off; off >>= 1) s += __shfl_xor(s, off, 64);
  const float d = s * (1.0f / NB);
  f32x4 o;
  #pragma unroll
  for (int j = 0; j < 4; j++) o[j] = (v[j] >= thr) ? v[j] / d : 0.f;
  *(f32x4*)&part[(size_t)row * NB + lane * 4] = o;
}

// ---------------- K3: main GEMM, BK=64 dbuf gload_lds + cheap p-fold --------
// (R11-measured 112us version — unchanged)
__global__ __launch_bounds__(256) void main_v5(
    const unsigned short* __restrict__ xht,
    const unsigned short* __restrict__ wtt,
    const float* __restrict__ g,
    const float* __restrict__ bias,
    float* __restrict__ out)
{
  __shared__ unsigned short XA[2][8192], WB[2][8192];  // 64 KB
  __shared__ float gl2[16 * 132];                      // [p][row], 8.4 KB

  const int f  = blockIdx.x;
  const int q  = f >> 6;
  const int bt = (f & 7) * 8 + ((f >> 3) & 7);   // XCD-aware: q-mates co-XCD
  const int b0 = bt * 128;
  const int t    = threadIdx.x;
  const int lane = t & 63;
  const int wid  = t >> 6;
  const int wr   = (wid >> 1) * 64;
  const int wc   = (wid & 1) * 64;
  const int l15  = lane & 15;
  const int l4   = lane >> 4;

  for (int e = t; e < 16 * 128; e += 256){
    const int p = e >> 7, r = e & 127;
    gl2[p * 132 + r] = g[(size_t)(b0 + r) * NB + p * 16 + q];
  }

  f32x4 accT[4][4];
  #pragma unroll
  for (int m = 0; m < 4; m++)
    #pragma unroll
    for (int n = 0; n < 4; n++) accT[m][n] = (f32x4)0.0f;
  const f32x4 z4 = (f32x4)0.0f;

  int aoff[2][4], boff[2][4];
  #pragma unroll
  for (int ksi = 0; ksi < 2; ksi++){
    #pragma unroll
    for (int m = 0; m < 4; m++){
      const int row = wr + m * 16 + l15;
      aoff[ksi][m] = ksi * 4096 + row * 32 + ((l4 ^ ((row >> 1) & 3)) << 3);
    }
    #pragma unroll
    for (int n = 0; n < 4; n++){
      const int row = wc + n * 16 + l15;
      boff[ksi][n] = ksi * 4096 + row * 32 + ((l4 ^ ((row >> 1) & 3)) << 3);
    }
  }

  const unsigned short* asrc0 = xht + (size_t)bt * 64 * 4096;
  const unsigned short* bsrc0 = wtt + (size_t)q  * 64 * 4096;

  auto GLOAD = [&](int bb, int s){       // stage 2 consecutive BK=32 images
    const unsigned short* as = asrc0 + (size_t)s * 8192;
    const unsigned short* bs = bsrc0 + (size_t)s * 8192;
    #pragma unroll
    for (int i = 0; i < 4; i++){
      const int sl = (wid * 4 + i) * 512;
      gload16(as + sl + lane * 8, &XA[bb][sl]);
      gload16(bs + sl + lane * 8, &WB[bb][sl]);
    }
  };

  GLOAD(0, 0);
  int buf = 0;
  #pragma unroll 1
  for (int pb = 0; pb < 16; pb++){
    f32x4 accP[4][4];
    #pragma unroll
    for (int s2 = 0; s2 < 2; s2++){
      const int s = pb * 2 + s2;
      __syncthreads();                  // DMA(buf) drained; prev reads done
      if (s < 31) GLOAD(buf ^ 1, s + 1);
      #pragma unroll
      for (int ksi = 0; ksi < 2; ksi++){
        bf16x8 a[4], b[4];
        #pragma unroll
        for (int m = 0; m < 4; m++) a[m] = *(const bf16x8*)&XA[buf][aoff[ksi][m]];
        #pragma unroll
        for (int n = 0; n < 4; n++) b[n] = *(const bf16x8*)&WB[buf][boff[ksi][n]];
        if (s2 == 0 && ksi == 0){
          #pragma unroll
          for (int m = 0; m < 4; m++)
            #pragma unroll
            for (int n = 0; n < 4; n++)
              accP[m][n] = __builtin_amdgcn_mfma_f32_16x16x32_bf16(a[m], b[n], z4, 0, 0, 0);
        } else {
          #pragma unroll
          for (int m = 0; m < 4; m++)
            #pragma unroll
            for (int n = 0; n < 4; n++)
              accP[m][n] = __builtin_amdgcn_mfma_f32_16x16x32_bf16(a[m], b[n], accP[m][n], 0, 0, 0);
        }
      }
      buf ^= 1;
    }
    #pragma unroll
    for (int m = 0; m < 4; m++){
      const f32x4 g4 = *(const f32x4*)&gl2[pb * 132 + wr + m * 16 + l4 * 4];
      #pragma unroll
      for (int n = 0; n < 4; n++)
        accT[m][n] += g4 * accP[m][n];
    }
  }

  #pragma unroll
  for (int n = 0; n < 4; n++){
    const int col = q * 128 + wc + n * 16 + l15;
    const float bv = bias[col];
    #pragma unroll
    for (int m = 0; m < 4; m++){
      #pragma unroll
      for (int r = 0; r < 4; r++){
        const int row = b0 + wr + m * 16 + l4 * 4 + r;
        out[(size_t)row * DOUT + col] = accT[m][n][r] + bv;
      }
    }
  }
}

// ---------------- launch -----------------------------------------------------
extern "C" void kernel_launch(void* const* d_in, const int* in_sizes, int n_in,
                              void* d_out, int out_size, void* d_ws, size_t ws_size,
                              hipStream_t stream)
{
  const float* x    = (const float*)d_in[0];
  const float* w    = (const float*)d_in[1];
  const float* bias = (const float*)d_in[2];
  const float* gw   = (const float*)d_in[3];
  const float* gb   = (const float*)d_in[4];
  float* out = (float*)d_out;

  // ws (<=50.1 MiB):
  //   [0,8M)   part split 0 (becomes final gates)
  //   [8,16M)  part split 1 (dead after topk) -> wtt (tiled W^T) after refine
  //   [16,48M) xht tiled bf16(x)
  //   [48,49M) ght | [49,50M) glt | [50M,+32K) flags
  // xlt (32 MB) lives in d_out scratch: written by conv_xhl, read by gate_v8,
  // then d_out fully overwritten by main_v5.
  char* wsb = (char*)d_ws;
  float*          part = (float*)wsb;
  unsigned short* wtt  = (unsigned short*)(wsb + (size_t)8  * 1024 * 1024);
  unsigned short* xht  = (unsigned short*)(wsb + (size_t)16 * 1024 * 1024);
  unsigned short* ght  = (unsigned short*)(wsb + (size_t)48 * 1024 * 1024);
  unsigned short* glt  = (unsigned short*)(wsb + (size_t)49 * 1024 * 1024);
  int*            flg  = (int*)           (wsb + (size_t)50 * 1024 * 1024);
  unsigned short* xlt  = (unsigned short*)d_out;

  conv_xhl <<<dim3(BATCH / 64, DIN / 128), 256, 0, stream>>>(x, xht, xlt);
  conv_gwt2<<<dim3(DIN / 64, NB / 64), 256, 0, stream>>>(gw, ght, glt);
  gate_v8  <<<dim3(BATCH / 64, 2), 256, 0, stream>>>(xht, xlt, ght, glt, part);
  topk     <<<BATCH / 4, 256, 0, stream>>>(part, gb, flg);
  refine   <<<BATCH / 4, 256, 0, stream>>>(x, gw, gb, flg, part);
  conv_wt2 <<<dim3(DIN / 64, DOUT / 64), 256, 0, stream>>>(w, wtt);
  main_v5  <<<1024, 256, 0, stream>>>(xht, wtt, part, bias, out);
}